// Round 1
// baseline (146.220 us; speedup 1.0000x reference)
//
#include <hip/hip_runtime.h>

#define NPRED 300
#define MTGT  64
#define NTHR  320
#define NWAVES (NTHR / 64)
#define BIGF  1e30f

// Compute cost Ct[i][j] = vmask[i] ? 5*L1(pred_j, tgt_i) - 2*IoU(pred_j, tgt_i) : 0
// Exact IEEE f32 op order matching the jax/numpy reference (no FMA contraction).
__device__ __forceinline__ float cost_ij(float p0, float p1, float p2, float p3,
                                         float area_p,
                                         float t0, float t1, float t2, float t3,
                                         float area_t, int vm)
{
    // cost_bbox = |p0-t0| + |p1-t1| + |p2-t2| + |p3-t3|  (sequential sum)
    float cb = fabsf(__fsub_rn(p0, t0));
    cb = __fadd_rn(cb, fabsf(__fsub_rn(p1, t1)));
    cb = __fadd_rn(cb, fabsf(__fsub_rn(p2, t2)));
    cb = __fadd_rn(cb, fabsf(__fsub_rn(p3, t3)));
    // IoU
    float ltx = fmaxf(p0, t0), lty = fmaxf(p1, t1);
    float rbx = fminf(p2, t2), rby = fminf(p3, t3);
    float w = fmaxf(__fsub_rn(rbx, ltx), 0.0f);
    float h = fmaxf(__fsub_rn(rby, lty), 0.0f);
    float inter = __fmul_rn(w, h);
    float uni = __fsub_rn(__fadd_rn(area_p, area_t), inter);
    float iou = __fdiv_rn(inter, __fadd_rn(uni, 1e-7f));
    // 5*cb + 2*(-iou)
    float c = __fadd_rn(__fmul_rn(5.0f, cb), __fmul_rn(2.0f, -iou));
    return vm ? c : 0.0f;
}

__global__ __launch_bounds__(NTHR)
void hungarian_kernel(const float* __restrict__ pred,   // [B, NPRED, 4]
                      const float* __restrict__ tgt,    // [B, MTGT, 4]
                      const int*   __restrict__ mask,   // [B, MTGT]
                      int* __restrict__ out,            // [2, B, MTGT]
                      int B)
{
    const int b    = blockIdx.x;
    const int tid  = threadIdx.x;
    const int lane = tid & 63;
    const int wid  = tid >> 6;

    __shared__ float t_box[MTGT][4];
    __shared__ float area_t_s[MTGT];
    __shared__ int   vmask[MTGT];
    __shared__ float u_s[MTGT];
    __shared__ int   col4row[MTGT];
    __shared__ int   SR[MTGT];
    __shared__ float v_s[NPRED];
    __shared__ float shortest[NPRED];
    __shared__ int   path[NPRED];
    __shared__ int   row4col[NPRED];
    __shared__ int   SC[NPRED];
    __shared__ float redv[NWAVES];
    __shared__ int   redi[NWAVES];
    __shared__ float s_minVal;
    __shared__ int   s_i;
    __shared__ int   s_sink;

    // ---- load per-batch data ----
    if (tid < MTGT) {
        const float* tb = tgt + ((size_t)b * MTGT + tid) * 4;
        float t0 = tb[0], t1 = tb[1], t2 = tb[2], t3 = tb[3];
        t_box[tid][0] = t0; t_box[tid][1] = t1;
        t_box[tid][2] = t2; t_box[tid][3] = t3;
        area_t_s[tid] = __fmul_rn(__fsub_rn(t2, t0), __fsub_rn(t3, t1));
        vmask[tid] = (mask[(size_t)b * MTGT + tid] > 0) ? 1 : 0;
        u_s[tid] = 0.0f;
        col4row[tid] = -1;
    }
    if (tid < NPRED) {
        v_s[tid] = 0.0f;
        row4col[tid] = -1;
    }

    // per-thread pred box (column tid)
    float p0 = 0.f, p1 = 0.f, p2 = 0.f, p3 = 0.f, area_p = 0.f;
    if (tid < NPRED) {
        const float* pb = pred + ((size_t)b * NPRED + tid) * 4;
        p0 = pb[0]; p1 = pb[1]; p2 = pb[2]; p3 = pb[3];
        area_p = __fmul_rn(__fsub_rn(p2, p0), __fsub_rn(p3, p1));
    }
    __syncthreads();

    // ---- LSAP: shortest augmenting path per target row ----
    for (int cur_row = 0; cur_row < MTGT; ++cur_row) {
        if (tid < NPRED) { shortest[tid] = BIGF; path[tid] = -1; SC[tid] = 0; }
        if (tid < MTGT)  { SR[tid] = 0; }
        if (tid == 0)    { s_i = cur_row; s_sink = -1; s_minVal = 0.0f; }
        __syncthreads();

        float minVal_f = 0.0f;
        int   sink_f   = -1;

        for (;;) {
            const int   i      = s_i;
            const int   sink   = s_sink;
            const float minVal = s_minVal;
            if (sink >= 0) { minVal_f = minVal; sink_f = sink; break; }

            if (tid == 0) SR[i] = 1;
            const float ui = u_s[i];
            const float t0 = t_box[i][0], t1 = t_box[i][1];
            const float t2 = t_box[i][2], t3 = t_box[i][3];
            const float at = area_t_s[i];
            const int   vm = vmask[i];

            float myv = BIGF;
            int   myi = tid;
            if (tid < NPRED) {
                if (!SC[tid]) {
                    float c = cost_ij(p0, p1, p2, p3, area_p, t0, t1, t2, t3, at, vm);
                    // r = ((minVal + c) - u[i]) - v[j]
                    float r = __fsub_rn(__fsub_rn(__fadd_rn(minVal, c), ui), v_s[tid]);
                    if (r < shortest[tid]) { shortest[tid] = r; path[tid] = i; }
                    myv = shortest[tid];
                }
            }

            // 64-lane butterfly argmin (first-index tie-break)
            float bv = myv; int bi = myi;
            #pragma unroll
            for (int off = 1; off < 64; off <<= 1) {
                float ov = __shfl_xor(bv, off);
                int   oi = __shfl_xor(bi, off);
                if (ov < bv || (ov == bv && oi < bi)) { bv = ov; bi = oi; }
            }
            if (lane == 0) { redv[wid] = bv; redi[wid] = bi; }
            __syncthreads();

            if (tid == 0) {
                float mv = redv[0]; int mj = redi[0];
                #pragma unroll
                for (int w = 1; w < NWAVES; ++w) {
                    if (redv[w] < mv || (redv[w] == mv && redi[w] < mj)) {
                        mv = redv[w]; mj = redi[w];
                    }
                }
                s_minVal = mv;
                SC[mj] = 1;
                int rc = row4col[mj];
                if (rc < 0) s_sink = mj;
                else        s_i    = rc;
            }
            __syncthreads();
        }

        // ---- dual updates (parallel) ----
        if (tid == cur_row) {
            u_s[tid] = __fadd_rn(u_s[tid], minVal_f);
        } else if (tid < MTGT && SR[tid]) {
            int c = col4row[tid];
            if (c < 0) c = 0;  // jnp.clip(col4row, 0)
            float d = __fsub_rn(minVal_f, shortest[c]);
            u_s[tid] = __fadd_rn(u_s[tid], d);
        }
        if (tid < NPRED && SC[tid]) {
            float d = __fsub_rn(minVal_f, shortest[tid]);
            v_s[tid] = __fsub_rn(v_s[tid], d);
        }
        __syncthreads();

        // ---- augment along alternating path (serial, thread 0) ----
        if (tid == 0) {
            int j = sink_f;
            int i = -1;
            while (i != cur_row) {
                i = path[j];
                row4col[j] = i;
                int jn = col4row[i];
                col4row[i] = j;
                j = jn;
            }
        }
        __syncthreads();
    }

    // ---- write outputs: pred_idx [B,MTGT], then tgt_idx [B,MTGT] ----
    if (tid < MTGT) {
        int vm = vmask[tid];
        out[(size_t)b * MTGT + tid] = vm ? col4row[tid] : -1;
        out[(size_t)B * MTGT + (size_t)b * MTGT + tid] = vm ? tid : -1;
    }
}

extern "C" void kernel_launch(void* const* d_in, const int* in_sizes, int n_in,
                              void* d_out, int out_size, void* d_ws, size_t ws_size,
                              hipStream_t stream)
{
    const float* pred = (const float*)d_in[0];
    const float* tgt  = (const float*)d_in[1];
    const int*   mask = (const int*)d_in[2];
    int* out = (int*)d_out;

    const int B = in_sizes[2] / MTGT;  // mask is [B, MTGT]

    hipLaunchKernelGGL(hungarian_kernel, dim3(B), dim3(NTHR), 0, stream,
                       pred, tgt, mask, out, B);
}

// Round 2
// 117.908 us; speedup vs baseline: 1.2401x; 1.2401x over previous
//
#include <hip/hip_runtime.h>

#define NPRED 300
#define MTGT  64
#define NTHR  256            // 4 waves for cost precompute; wave 0 solves
#define NSLOT 5              // columns per lane: j = k*64 + lane, k = 0..4
#define BIGF  1e30f
#define LDS_FLOATS (MTGT * NPRED + 64)   // +64 pad so k=4 reads never go OOB

// Exact IEEE f32 op order matching the jax/numpy reference (no FMA contraction).
__device__ __forceinline__ float cost_ij(float p0, float p1, float p2, float p3,
                                         float t0, float t1, float t2, float t3)
{
    float area_p = __fmul_rn(__fsub_rn(p2, p0), __fsub_rn(p3, p1));
    float area_t = __fmul_rn(__fsub_rn(t2, t0), __fsub_rn(t3, t1));
    float cb = fabsf(__fsub_rn(p0, t0));
    cb = __fadd_rn(cb, fabsf(__fsub_rn(p1, t1)));
    cb = __fadd_rn(cb, fabsf(__fsub_rn(p2, t2)));
    cb = __fadd_rn(cb, fabsf(__fsub_rn(p3, t3)));
    float ltx = fmaxf(p0, t0), lty = fmaxf(p1, t1);
    float rbx = fminf(p2, t2), rby = fminf(p3, t3);
    float w = fmaxf(__fsub_rn(rbx, ltx), 0.0f);
    float h = fmaxf(__fsub_rn(rby, lty), 0.0f);
    float inter = __fmul_rn(w, h);
    float uni = __fsub_rn(__fadd_rn(area_p, area_t), inter);
    float iou = __fdiv_rn(inter, __fadd_rn(uni, 1e-7f));
    return __fadd_rn(__fmul_rn(5.0f, cb), __fmul_rn(2.0f, -iou));
}

__global__ __launch_bounds__(NTHR)
void hungarian_kernel(const float* __restrict__ pred,   // [B, NPRED, 4]
                      const float* __restrict__ tgt,    // [B, MTGT, 4]
                      const int*   __restrict__ mask,   // [B, MTGT]
                      int* __restrict__ out,            // [2, B, MTGT]
                      int B)
{
    extern __shared__ float Cmat[];        // [MTGT][NPRED] + pad
    const int b   = blockIdx.x;
    const int tid = threadIdx.x;

    const float* pb_base = pred + (size_t)b * NPRED * 4;
    const float* tb_base = tgt  + (size_t)b * MTGT  * 4;
    const int*   mk      = mask + (size_t)b * MTGT;

    // ---- precompute cost matrix with all 4 waves (75 entries/thread) ----
    for (int e = tid; e < MTGT * NPRED; e += NTHR) {
        int i = e / NPRED;
        int j = e - i * NPRED;
        const float* pb = pb_base + j * 4;
        const float* tb = tb_base + i * 4;
        float c = cost_ij(pb[0], pb[1], pb[2], pb[3], tb[0], tb[1], tb[2], tb[3]);
        Cmat[e] = (mk[i] > 0) ? c : 0.0f;
    }
    if (tid < 64) Cmat[MTGT * NPRED + tid] = 0.0f;   // zero the pad
    __syncthreads();
    if (tid >= 64) return;                 // waves 1-3 done; no barriers below

    // ================= single-wave solver: lane = tid =================
    const int lane = tid;
    const int vm   = mk[lane] > 0;

    float vdual[NSLOT];                    // v[j] for j = k*64+lane
    float sh[NSLOT];                       // shortest[j]
    int   pth[NSLOT];                      // path[j]
    #pragma unroll
    for (int k = 0; k < NSLOT; ++k) vdual[k] = 0.0f;
    float u   = 0.0f;                      // u[row=lane]
    int   c4r = -1;                        // col4row[row=lane]

    const int sc_init = (lane < (NPRED - 4 * 64)) ? 0 : (1 << 4);  // j>=300 dead

    for (int cur_row = 0; cur_row < MTGT; ++cur_row) {
        #pragma unroll
        for (int k = 0; k < NSLOT; ++k) { sh[k] = BIGF; pth[k] = -1; }
        int   SCm    = sc_init;
        int   SRb    = 0;
        float minVal = 0.0f;
        int   i      = cur_row;
        int   sink;

        for (;;) {
            if (lane == i) SRb = 1;
            const float u_i  = __shfl(u, i);
            const float* crow = &Cmat[i * NPRED];

            float bv = BIGF; int bj = lane;
            #pragma unroll
            for (int k = 0; k < NSLOT; ++k) {
                const int  j   = k * 64 + lane;
                const bool act = !((SCm >> k) & 1);
                float c = crow[k * 64 + lane];            // pad covers i=63,k=4
                float r = __fsub_rn(__fsub_rn(__fadd_rn(minVal, c), u_i), vdual[k]);
                if (act && r < sh[k]) { sh[k] = r; pth[k] = i; }
                float cand = act ? sh[k] : BIGF;
                if (cand < bv) { bv = cand; bj = j; }     // lower k = lower j on tie
            }
            // 64-lane butterfly argmin, first-index tie-break
            #pragma unroll
            for (int off = 1; off < 64; off <<= 1) {
                float ov = __shfl_xor(bv, off);
                int   oj = __shfl_xor(bj, off);
                if (ov < bv || (ov == bv && oj < bj)) { bv = ov; bj = oj; }
            }
            minVal = bv;
            if (lane == (bj & 63)) SCm |= 1 << (bj >> 6);     // SC[bj] = true
            unsigned long long mch = __ballot(c4r == bj);     // row4col lookup
            if (mch == 0ULL) { sink = bj; break; }            // free column
            i = (int)__builtin_ctzll(mch);
        }

        // ---- dual updates ----
        {
            int c  = c4r < 0 ? 0 : c4r;                 // clip(col4row, 0)
            int cl = c & 63, cs = c >> 6;
            float g[NSLOT];
            #pragma unroll
            for (int k = 0; k < NSLOT; ++k) g[k] = __shfl(sh[k], cl);
            float sv = cs == 0 ? g[0] : cs == 1 ? g[1] : cs == 2 ? g[2]
                     : cs == 3 ? g[3] : g[4];
            if (lane == cur_row)      u = __fadd_rn(u, minVal);
            else if (SRb)             u = __fadd_rn(u, __fsub_rn(minVal, sv));
            #pragma unroll
            for (int k = 0; k < NSLOT; ++k) {
                const int j = k * 64 + lane;
                if (j < NPRED && ((SCm >> k) & 1))
                    vdual[k] = __fsub_rn(vdual[k], __fsub_rn(minVal, sh[k]));
            }
        }

        // ---- augment along alternating path (uniform control flow) ----
        {
            int j  = sink;
            int ia = -1;
            while (ia != cur_row) {
                int jl = j & 63, js = j >> 6;
                int pv[NSLOT];
                #pragma unroll
                for (int k = 0; k < NSLOT; ++k) pv[k] = __shfl(pth[k], jl);
                ia = js == 0 ? pv[0] : js == 1 ? pv[1] : js == 2 ? pv[2]
                   : js == 3 ? pv[3] : pv[4];
                int jn = __shfl(c4r, ia);               // old col4row[ia]
                if (lane == ia) c4r = j;
                j = jn;
            }
        }
    }

    out[(size_t)b * MTGT + lane]                         = vm ? c4r : -1;
    out[(size_t)B * MTGT + (size_t)b * MTGT + lane]      = vm ? lane : -1;
}

extern "C" void kernel_launch(void* const* d_in, const int* in_sizes, int n_in,
                              void* d_out, int out_size, void* d_ws, size_t ws_size,
                              hipStream_t stream)
{
    const float* pred = (const float*)d_in[0];
    const float* tgt  = (const float*)d_in[1];
    const int*   mask = (const int*)d_in[2];
    int* out = (int*)d_out;

    const int B = in_sizes[2] / MTGT;   // mask is [B, MTGT]
    const size_t lds_bytes = LDS_FLOATS * sizeof(float);   // 77 KB > 64 KB: opt in

    (void)hipFuncSetAttribute((const void*)hungarian_kernel,
                              hipFuncAttributeMaxDynamicSharedMemorySize,
                              (int)lds_bytes);

    hipLaunchKernelGGL(hungarian_kernel, dim3(B), dim3(NTHR), lds_bytes, stream,
                       pred, tgt, mask, out, B);
}

// Round 3
// 99.765 us; speedup vs baseline: 1.4656x; 1.1819x over previous
//
#include <hip/hip_runtime.h>

#define NPRED 300
#define MTGT  64
#define NTHR  256            // 4 waves for cost precompute; wave 0 solves
#define NSLOT 5              // columns per lane: j = k*64 + lane, k = 0..4
#define BIGF  1e30f
#define LDS_FLOATS (MTGT * NPRED + 64)   // +64 pad so k=4 reads never go OOB

// Exact IEEE f32 op order matching the jax/numpy reference (no FMA contraction).
__device__ __forceinline__ float cost_ij(float p0, float p1, float p2, float p3,
                                         float t0, float t1, float t2, float t3)
{
    float area_p = __fmul_rn(__fsub_rn(p2, p0), __fsub_rn(p3, p1));
    float area_t = __fmul_rn(__fsub_rn(t2, t0), __fsub_rn(t3, t1));
    float cb = fabsf(__fsub_rn(p0, t0));
    cb = __fadd_rn(cb, fabsf(__fsub_rn(p1, t1)));
    cb = __fadd_rn(cb, fabsf(__fsub_rn(p2, t2)));
    cb = __fadd_rn(cb, fabsf(__fsub_rn(p3, t3)));
    float ltx = fmaxf(p0, t0), lty = fmaxf(p1, t1);
    float rbx = fminf(p2, t2), rby = fminf(p3, t3);
    float w = fmaxf(__fsub_rn(rbx, ltx), 0.0f);
    float h = fmaxf(__fsub_rn(rby, lty), 0.0f);
    float inter = __fmul_rn(w, h);
    float uni = __fsub_rn(__fadd_rn(area_p, area_t), inter);
    float iou = __fdiv_rn(inter, __fadd_rn(uni, 1e-7f));
    return __fadd_rn(__fmul_rn(5.0f, cb), __fmul_rn(2.0f, -iou));
}

// One lex-min (val, idx) combine step over a DPP lane-pattern. Identity for
// invalid lanes = (BIGF, INT_MAX) so they can never win (strict < / tie idx <).
template<int CTRL>
__device__ __forceinline__ void dpp_min_step(float& bv, int& bj)
{
    int ov_i = __builtin_amdgcn_update_dpp(__float_as_int(BIGF),
                                           __float_as_int(bv),
                                           CTRL, 0xF, 0xF, false);
    int oj   = __builtin_amdgcn_update_dpp(0x7FFFFFFF, bj,
                                           CTRL, 0xF, 0xF, false);
    float ov = __int_as_float(ov_i);
    if (ov < bv || (ov == bv && oj < bj)) { bv = ov; bj = oj; }
}

__global__ __launch_bounds__(NTHR)
void hungarian_kernel(const float* __restrict__ pred,   // [B, NPRED, 4]
                      const float* __restrict__ tgt,    // [B, MTGT, 4]
                      const int*   __restrict__ mask,   // [B, MTGT]
                      int* __restrict__ out,            // [2, B, MTGT]
                      int B)
{
    extern __shared__ float Cmat[];        // [MTGT][NPRED] + pad
    const int b   = blockIdx.x;
    const int tid = threadIdx.x;

    const float* pb_base = pred + (size_t)b * NPRED * 4;
    const float* tb_base = tgt  + (size_t)b * MTGT  * 4;
    const int*   mk      = mask + (size_t)b * MTGT;

    // ---- precompute cost matrix with all 4 waves (75 entries/thread) ----
    for (int e = tid; e < MTGT * NPRED; e += NTHR) {
        int i = e / NPRED;
        int j = e - i * NPRED;
        const float* pb = pb_base + j * 4;
        const float* tb = tb_base + i * 4;
        float c = cost_ij(pb[0], pb[1], pb[2], pb[3], tb[0], tb[1], tb[2], tb[3]);
        Cmat[e] = (mk[i] > 0) ? c : 0.0f;
    }
    if (tid < 64) Cmat[MTGT * NPRED + tid] = 0.0f;   // zero the pad
    __syncthreads();
    if (tid >= 64) return;                 // waves 1-3 done; no barriers below

    // ================= single-wave solver: lane = tid =================
    const int lane = tid;
    const int vm   = mk[lane] > 0;

    float vdual[NSLOT];                    // v[j] for j = k*64+lane
    float sh[NSLOT];                       // shortest[j]
    int   pth[NSLOT];                      // path[j]
    #pragma unroll
    for (int k = 0; k < NSLOT; ++k) vdual[k] = 0.0f;
    float u   = 0.0f;                      // u[row=lane]
    int   c4r = -1;                        // col4row[row=lane]

    const int sc_init = (lane < (NPRED - 4 * 64)) ? 0 : (1 << 4);  // j>=300 dead

    for (int cur_row = 0; cur_row < MTGT; ++cur_row) {
        #pragma unroll
        for (int k = 0; k < NSLOT; ++k) { sh[k] = BIGF; pth[k] = -1; }
        int   SCm    = sc_init;
        int   SRb    = 0;
        float minVal = 0.0f;               // lane-uniform
        int   i      = cur_row;            // lane-uniform
        int   sink;

        for (;;) {
            SRb |= (lane == i);
            const float u_i =
                __int_as_float(__builtin_amdgcn_readlane(__float_as_int(u), i));
            const float* crow = &Cmat[i * NPRED];

            // per-slot relax + local argmin tree (first-k = first-j tie-break)
            float cand[NSLOT];
            #pragma unroll
            for (int k = 0; k < NSLOT; ++k) {
                float c = crow[k * 64 + lane];            // pad covers i=63,k=4
                float r = __fsub_rn(__fsub_rn(__fadd_rn(minVal, c), u_i), vdual[k]);
                bool act = !((SCm >> k) & 1);
                if (act && r < sh[k]) { sh[k] = r; pth[k] = i; }
                cand[k] = act ? sh[k] : BIGF;
            }
            float v01 = cand[0]; int k01 = 0;
            if (cand[1] < v01) { v01 = cand[1]; k01 = 1; }
            float v23 = cand[2]; int k23 = 2;
            if (cand[3] < v23) { v23 = cand[3]; k23 = 3; }
            float vt = v01; int kt = k01;
            if (v23 < vt) { vt = v23; kt = k23; }
            if (cand[4] < vt) { vt = cand[4]; kt = 4; }

            float bv = vt;
            int   bj = (kt << 6) | lane;                  // global column index

            // 64-lane lex-min via DPP (VALU pipe, no LDS traffic)
            dpp_min_step<0x111>(bv, bj);   // row_shr:1
            dpp_min_step<0x112>(bv, bj);   // row_shr:2
            dpp_min_step<0x114>(bv, bj);   // row_shr:4
            dpp_min_step<0x118>(bv, bj);   // row_shr:8
            dpp_min_step<0x142>(bv, bj);   // row_bcast15
            dpp_min_step<0x143>(bv, bj);   // row_bcast31
            const int   bj_s = __builtin_amdgcn_readlane(bj, 63);
            const float mv_s =
                __int_as_float(__builtin_amdgcn_readlane(__float_as_int(bv), 63));

            minVal = mv_s;
            if (lane == (bj_s & 63)) SCm |= 1 << (bj_s >> 6);   // SC[bj] = true
            unsigned long long mch = __ballot(c4r == bj_s);     // row4col lookup
            if (mch == 0ULL) { sink = bj_s; break; }            // free column
            i = (int)__builtin_ctzll(mch);
        }

        // ---- dual updates ----
        {
            int c  = c4r < 0 ? 0 : c4r;                 // clip(col4row, 0)
            int cl = c & 63, cs = c >> 6;
            float g[NSLOT];
            #pragma unroll
            for (int k = 0; k < NSLOT; ++k) g[k] = __shfl(sh[k], cl);
            float sv = cs == 0 ? g[0] : cs == 1 ? g[1] : cs == 2 ? g[2]
                     : cs == 3 ? g[3] : g[4];
            if (lane == cur_row)      u = __fadd_rn(u, minVal);
            else if (SRb)             u = __fadd_rn(u, __fsub_rn(minVal, sv));
            #pragma unroll
            for (int k = 0; k < NSLOT; ++k) {
                const int j = k * 64 + lane;
                if (j < NPRED && ((SCm >> k) & 1))
                    vdual[k] = __fsub_rn(vdual[k], __fsub_rn(minVal, sh[k]));
            }
        }

        // ---- augment along alternating path (uniform, readlane-based) ----
        {
            int j  = sink;
            int ia = -1;
            while (ia != cur_row) {
                int jl = j & 63, js = j >> 6;
                int p0r = __builtin_amdgcn_readlane(pth[0], jl);
                int p1r = __builtin_amdgcn_readlane(pth[1], jl);
                int p2r = __builtin_amdgcn_readlane(pth[2], jl);
                int p3r = __builtin_amdgcn_readlane(pth[3], jl);
                int p4r = __builtin_amdgcn_readlane(pth[4], jl);
                ia = js == 0 ? p0r : js == 1 ? p1r : js == 2 ? p2r
                   : js == 3 ? p3r : p4r;
                int jn = __builtin_amdgcn_readlane(c4r, ia);   // old col4row[ia]
                if (lane == ia) c4r = j;
                j = jn;
            }
        }
    }

    out[(size_t)b * MTGT + lane]                    = vm ? c4r : -1;
    out[(size_t)B * MTGT + (size_t)b * MTGT + lane] = vm ? lane : -1;
}

extern "C" void kernel_launch(void* const* d_in, const int* in_sizes, int n_in,
                              void* d_out, int out_size, void* d_ws, size_t ws_size,
                              hipStream_t stream)
{
    const float* pred = (const float*)d_in[0];
    const float* tgt  = (const float*)d_in[1];
    const int*   mask = (const int*)d_in[2];
    int* out = (int*)d_out;

    const int B = in_sizes[2] / MTGT;   // mask is [B, MTGT]
    const size_t lds_bytes = LDS_FLOATS * sizeof(float);   // 77 KB > 64 KB: opt in

    (void)hipFuncSetAttribute((const void*)hungarian_kernel,
                              hipFuncAttributeMaxDynamicSharedMemorySize,
                              (int)lds_bytes);

    hipLaunchKernelGGL(hungarian_kernel, dim3(B), dim3(NTHR), lds_bytes, stream,
                       pred, tgt, mask, out, B);
}

// Round 4
// 72.997 us; speedup vs baseline: 2.0031x; 1.3667x over previous
//
#include <hip/hip_runtime.h>

#define NPRED 300
#define MTGT  64
#define NTHR  256            // 4 waves for cost precompute; wave 0 solves
#define NSLOT 5              // columns per lane: j = k*64 + lane, k = 0..4
#define BIGF  1e30f
#define LDS_FLOATS (MTGT * NPRED + 64)   // +64 pad so k=4 reads never go OOB

// Exact IEEE f32 op order matching the jax/numpy reference (no FMA contraction).
__device__ __forceinline__ float cost_ij(float p0, float p1, float p2, float p3,
                                         float t0, float t1, float t2, float t3)
{
    float area_p = __fmul_rn(__fsub_rn(p2, p0), __fsub_rn(p3, p1));
    float area_t = __fmul_rn(__fsub_rn(t2, t0), __fsub_rn(t3, t1));
    float cb = fabsf(__fsub_rn(p0, t0));
    cb = __fadd_rn(cb, fabsf(__fsub_rn(p1, t1)));
    cb = __fadd_rn(cb, fabsf(__fsub_rn(p2, t2)));
    cb = __fadd_rn(cb, fabsf(__fsub_rn(p3, t3)));
    float ltx = fmaxf(p0, t0), lty = fmaxf(p1, t1);
    float rbx = fminf(p2, t2), rby = fminf(p3, t3);
    float w = fmaxf(__fsub_rn(rbx, ltx), 0.0f);
    float h = fmaxf(__fsub_rn(rby, lty), 0.0f);
    float inter = __fmul_rn(w, h);
    float uni = __fsub_rn(__fadd_rn(area_p, area_t), inter);
    float iou = __fdiv_rn(inter, __fadd_rn(uni, 1e-7f));
    return __fadd_rn(__fmul_rn(5.0f, cb), __fmul_rn(2.0f, -iou));
}

// Value-only DPP min steps. Invalid source lanes read identity (old).
template<int CTRL>
__device__ __forceinline__ float dppminf(float x)
{
    int m = __builtin_amdgcn_update_dpp(__float_as_int(BIGF), __float_as_int(x),
                                        CTRL, 0xF, 0xF, false);
    return fminf(x, __int_as_float(m));
}
template<int CTRL>
__device__ __forceinline__ unsigned dppminu(unsigned x)
{
    unsigned m = (unsigned)__builtin_amdgcn_update_dpp(0x7FFFFFFF, (int)x,
                                                       CTRL, 0xF, 0xF, false);
    return x < m ? x : m;
}

__device__ __forceinline__ float readlane_f(float x, int l)
{
    return __int_as_float(__builtin_amdgcn_readlane(__float_as_int(x), l));
}

__global__ __launch_bounds__(NTHR)
void hungarian_kernel(const float* __restrict__ pred,   // [B, NPRED, 4]
                      const float* __restrict__ tgt,    // [B, MTGT, 4]
                      const int*   __restrict__ mask,   // [B, MTGT]
                      int* __restrict__ out,            // [2, B, MTGT]
                      int B)
{
    extern __shared__ float Cmat[];        // [MTGT][NPRED] + pad
    const int b   = blockIdx.x;
    const int tid = threadIdx.x;

    const float* pb_base = pred + (size_t)b * NPRED * 4;
    const float* tb_base = tgt  + (size_t)b * MTGT  * 4;
    const int*   mk      = mask + (size_t)b * MTGT;

    // ---- precompute cost matrix with all 4 waves (75 entries/thread) ----
    for (int e = tid; e < MTGT * NPRED; e += NTHR) {
        int i = e / NPRED;
        int j = e - i * NPRED;
        const float* pb = pb_base + j * 4;
        const float* tb = tb_base + i * 4;
        float c = cost_ij(pb[0], pb[1], pb[2], pb[3], tb[0], tb[1], tb[2], tb[3]);
        Cmat[e] = (mk[i] > 0) ? c : 0.0f;
    }
    if (tid < 64) Cmat[MTGT * NPRED + tid] = 0.0f;   // zero the pad
    __syncthreads();
    if (tid >= 64) return;                 // waves 1-3 done; no barriers below

    // ================= single-wave solver: lane = tid =================
    const int lane = tid;
    const int vm   = mk[lane] > 0;

    float vdual[NSLOT];                    // v[j] for j = k*64+lane
    float sh[NSLOT];                       // shortest[j]
    int   pth[NSLOT];                      // path[j]
    int   r4c1[NSLOT];                     // row4col[j]+1 (0 = free)
    #pragma unroll
    for (int k = 0; k < NSLOT; ++k) { vdual[k] = 0.0f; r4c1[k] = 0; }
    float u   = 0.0f;                      // u[row=lane]
    int   c4r = -1;                        // col4row[row=lane]

    const int sc_init = (lane < (NPRED - 4 * 64)) ? 0 : (1 << 4);  // j>=300 dead

    for (int cur_row = 0; cur_row < MTGT; ++cur_row) {
        #pragma unroll
        for (int k = 0; k < NSLOT; ++k) { sh[k] = BIGF; pth[k] = -1; }
        int   SCm    = sc_init;
        int   SRb    = 0;
        float minVal = 0.0f;               // lane-uniform
        int   i      = cur_row;            // lane-uniform (scalar)
        int   sink;

        for (;;) {
            const float u_i  = readlane_f(u, i);
            const float* crow = &Cmat[i * NPRED];
            // issue the 5 LDS reads ASAP (single vaddr + imm offsets)
            float c0 = crow[0 * 64 + lane];
            float c1 = crow[1 * 64 + lane];
            float c2 = crow[2 * 64 + lane];
            float c3 = crow[3 * 64 + lane];
            float c4 = crow[4 * 64 + lane];            // pad covers i=63

            SRb |= (lane == i);

            // ---- old-shortest tree (independent of the loads; hides latency)
            // aux = (k<<8) | (owner+1); smaller aux == smaller j for distinct k
            float ov0, ov1; unsigned oa0, oa1;
            {
                float a0 = (SCm & 1)  ? BIGF : sh[0];
                float a1 = (SCm & 2)  ? BIGF : sh[1];
                float a2 = (SCm & 4)  ? BIGF : sh[2];
                float a3 = (SCm & 8)  ? BIGF : sh[3];
                float a4 = (SCm & 16) ? BIGF : sh[4];
                unsigned x0 = (0u << 8) | (unsigned)r4c1[0];
                unsigned x1 = (1u << 8) | (unsigned)r4c1[1];
                unsigned x2 = (2u << 8) | (unsigned)r4c1[2];
                unsigned x3 = (3u << 8) | (unsigned)r4c1[3];
                unsigned x4 = (4u << 8) | (unsigned)r4c1[4];
                float m01 = a0; unsigned q01 = x0;
                if (a1 < m01) { m01 = a1; q01 = x1; }
                float m23 = a2; unsigned q23 = x2;
                if (a3 < m23) { m23 = a3; q23 = x3; }
                ov0 = m01; oa0 = q01;
                if (m23 < ov0) { ov0 = m23; oa0 = q23; }
                ov1 = a4; oa1 = x4;
            }
            float vo = ov0; unsigned ao = oa0;
            if (ov1 < vo) { vo = ov1; ao = oa1; }

            // ---- relax with freshly-loaded costs (exact reference op order)
            float r0 = __fsub_rn(__fsub_rn(__fadd_rn(minVal, c0), u_i), vdual[0]);
            float r1 = __fsub_rn(__fsub_rn(__fadd_rn(minVal, c1), u_i), vdual[1]);
            float r2 = __fsub_rn(__fsub_rn(__fadd_rn(minVal, c2), u_i), vdual[2]);
            float r3 = __fsub_rn(__fsub_rn(__fadd_rn(minVal, c3), u_i), vdual[3]);
            float r4 = __fsub_rn(__fsub_rn(__fadd_rn(minVal, c4), u_i), vdual[4]);
            float rr[NSLOT] = { r0, r1, r2, r3, r4 };
            float cr[NSLOT];
            #pragma unroll
            for (int k = 0; k < NSLOT; ++k) {
                bool act = !((SCm >> k) & 1);
                bool upd = act && (rr[k] < sh[k]);
                sh[k]  = upd ? rr[k] : sh[k];
                pth[k] = upd ? i : pth[k];
                cr[k]  = act ? rr[k] : BIGF;
            }
            // new-r tree (k ascending; keep-first on tie)
            float nv; unsigned na;
            {
                float m01 = cr[0]; unsigned q01 = (0u << 8) | (unsigned)r4c1[0];
                if (cr[1] < m01) { m01 = cr[1]; q01 = (1u << 8) | (unsigned)r4c1[1]; }
                float m23 = cr[2]; unsigned q23 = (2u << 8) | (unsigned)r4c1[2];
                if (cr[3] < m23) { m23 = cr[3]; q23 = (3u << 8) | (unsigned)r4c1[3]; }
                nv = m01; na = q01;
                if (m23 < nv) { nv = m23; na = q23; }
                if (cr[4] < nv) { nv = cr[4]; na = (4u << 8) | (unsigned)r4c1[4]; }
            }
            // merge old/new (lex on (val, aux) — aux order == j order)
            bool tn = (nv < vo) || (nv == vo && na < ao);
            float    vt = tn ? nv : vo;
            unsigned at = tn ? na : ao;

            // ---- 64-lane value-only DPP min ----
            float red = vt;
            red = dppminf<0x111>(red);   // row_shr:1
            red = dppminf<0x112>(red);   // row_shr:2
            red = dppminf<0x114>(red);   // row_shr:4
            red = dppminf<0x118>(red);   // row_shr:8
            red = dppminf<0x142>(red);   // row_bcast15
            red = dppminf<0x143>(red);   // row_bcast31
            const float mv = readlane_f(red, 63);

            // ---- winner lane + (k, owner) recovery ----
            unsigned long long eqm = __ballot(vt == mv);
            int wl, kown;
            if (__popcll(eqm) == 1) {                       // unique min (common)
                wl   = (int)__builtin_ctzll(eqm);
                kown = __builtin_amdgcn_readlane((int)at, wl);
            } else {                                        // exact-tie slow path
                unsigned bjc = (vt == mv) ? (((at >> 8) << 6) | (unsigned)lane)
                                          : 0x7FFFFFFFu;
                bjc = dppminu<0x111>(bjc);
                bjc = dppminu<0x112>(bjc);
                bjc = dppminu<0x114>(bjc);
                bjc = dppminu<0x118>(bjc);
                bjc = dppminu<0x142>(bjc);
                bjc = dppminu<0x143>(bjc);
                int bj = __builtin_amdgcn_readlane((int)bjc, 63);
                wl   = bj & 63;
                kown = __builtin_amdgcn_readlane((int)at, wl);
            }
            const int kw = kown >> 8;          // winning slot k
            const int ow = kown & 0xFF;        // row4col[bj]+1 (0 = free)
            const int bj = (kw << 6) | wl;     // winning column j

            minVal = mv;
            // SC[bj] = true
            int nb = SCm | (1 << kw);
            SCm = (lane == wl) ? nb : SCm;

            if (ow == 0) { sink = bj; break; } // free column found
            i = ow - 1;                        // continue from its owner row
        }

        // ---- dual updates ----
        {
            int c  = c4r < 0 ? 0 : c4r;                 // clip(col4row, 0)
            int cl = c & 63, cs = c >> 6;
            float g[NSLOT];
            #pragma unroll
            for (int k = 0; k < NSLOT; ++k) g[k] = __shfl(sh[k], cl);
            float sv = cs == 0 ? g[0] : cs == 1 ? g[1] : cs == 2 ? g[2]
                     : cs == 3 ? g[3] : g[4];
            if (lane == cur_row)      u = __fadd_rn(u, minVal);
            else if (SRb)             u = __fadd_rn(u, __fsub_rn(minVal, sv));
            #pragma unroll
            for (int k = 0; k < NSLOT; ++k) {
                const int j = k * 64 + lane;
                if (j < NPRED && ((SCm >> k) & 1))
                    vdual[k] = __fsub_rn(vdual[k], __fsub_rn(minVal, sh[k]));
            }
        }

        // ---- augment along alternating path (uniform, readlane-based) ----
        {
            int j  = sink;
            int ia = -1;
            while (ia != cur_row) {
                int jl = j & 63, js = j >> 6;
                int p0r = __builtin_amdgcn_readlane(pth[0], jl);
                int p1r = __builtin_amdgcn_readlane(pth[1], jl);
                int p2r = __builtin_amdgcn_readlane(pth[2], jl);
                int p3r = __builtin_amdgcn_readlane(pth[3], jl);
                int p4r = __builtin_amdgcn_readlane(pth[4], jl);
                ia = js == 0 ? p0r : js == 1 ? p1r : js == 2 ? p2r
                   : js == 3 ? p3r : p4r;
                // row4col[j] = ia  (per-lane replicated table, +1 encoding)
                #pragma unroll
                for (int k = 0; k < NSLOT; ++k) {
                    bool sel = (js == k) && (lane == jl);
                    r4c1[k] = sel ? (ia + 1) : r4c1[k];
                }
                int jn = __builtin_amdgcn_readlane(c4r, ia);   // old col4row[ia]
                if (lane == ia) c4r = j;
                j = jn;
            }
        }
    }

    out[(size_t)b * MTGT + lane]                    = vm ? c4r : -1;
    out[(size_t)B * MTGT + (size_t)b * MTGT + lane] = vm ? lane : -1;
}

extern "C" void kernel_launch(void* const* d_in, const int* in_sizes, int n_in,
                              void* d_out, int out_size, void* d_ws, size_t ws_size,
                              hipStream_t stream)
{
    const float* pred = (const float*)d_in[0];
    const float* tgt  = (const float*)d_in[1];
    const int*   mask = (const int*)d_in[2];
    int* out = (int*)d_out;

    const int B = in_sizes[2] / MTGT;   // mask is [B, MTGT]
    const size_t lds_bytes = LDS_FLOATS * sizeof(float);   // 77 KB > 64 KB: opt in

    (void)hipFuncSetAttribute((const void*)hungarian_kernel,
                              hipFuncAttributeMaxDynamicSharedMemorySize,
                              (int)lds_bytes);

    hipLaunchKernelGGL(hungarian_kernel, dim3(B), dim3(NTHR), lds_bytes, stream,
                       pred, tgt, mask, out, B);
}